// Round 9
// baseline (36.501 us; speedup 1.0000x reference)
//
#include <hip/hip_runtime.h>

// Problem constants (from reference)
#define B_    16
#define N_    8192
#define FEAT_ 256
#define MEM_  128
#define U_    512

#define CHUNKS  32
#define ROWS    (N_ / CHUNKS)    // 256 rows per colsum block
#define CSTRIDE 32               // per-batch counter stride in uints (128 B)

// ---------------------------------------------------------------------------
// Exact algebraic reduction of the reference:
//   softmax over u then mean over the SAME u axis => attn rows sum to 1
//   out[b,:] = relu( ((S_b @ Wv + N*bv)/U) @ Wo + bo ),  S_b[f] = sum_n X[b,n,f]
// K, mem, Wk, bk, scores, softmax are all mathematically dead.
//
// SINGLE fused kernel. History of the cross-block handoff:
//   round 3: per-block __threadfence -> serialized L2 writebacks, 135 us.
//   round 6: protocol CORRECT (sc0sc1 store + vmcnt(0) + atomic + memset'd
//            counters, absolute election) but 1024 atomics on ONE cache line
//            serialized (+24 us) -> 53 us.
//   round 8: removed memset, modular election -> WRONG (winner is the 22nd
//            arriver when the counter starts at poison; reads unwritten part).
// This version = round 6's proven-correct protocol + round 8's cost fixes:
//   * per-batch counters on their OWN 128-B lines (16 lines, <=32 pipelined
//     RMWs each, ~1 us total, hidden under streaming).
//   * counters zeroed by one 2 KB graph-capturable hipMemsetAsync.
//   * absolute election: old == CHUNKS-1 -> winner is the TRUE last arriver.
//   * no weight pre-pass, no spins: the winner does the two-step matvec
//     directly (weights L3-hot, coalesced) -> no deadlock possible.
// Deterministic: all sums fixed-order fp32; any winner computes identically.
// ---------------------------------------------------------------------------

__device__ inline void store_f128_sc(float* p, float4 v) {
    typedef float f4v __attribute__((ext_vector_type(4)));
    f4v w; w[0] = v.x; w[1] = v.y; w[2] = v.z; w[3] = v.w;
    asm volatile("global_store_dwordx4 %0, %1, off sc0 sc1" :: "v"(p), "v"(w) : "memory");
}
__device__ inline void wait_vm0() {
    asm volatile("s_waitcnt vmcnt(0)" ::: "memory");
}

__global__ __launch_bounds__(256) void fused_all(
    const float* __restrict__ X,
    const float* __restrict__ Wv, const float* __restrict__ bv,
    const float* __restrict__ Wo, const float* __restrict__ bo,
    float* __restrict__ part,     // [B][CHUNKS][FEAT]
    unsigned* __restrict__ cnt,   // [B] counters, CSTRIDE-strided lines
    float* __restrict__ out) {
    const int bid   = blockIdx.x;
    const int chunk = bid & (CHUNKS - 1);
    const int b     = bid >> 5;
    const int tid   = threadIdx.x;
    const int f4    = tid & 63;   // which float4 of the 256-feature row
    const int phase = tid >> 6;   // 0..3 row phase

    __shared__ float4 sacc[256];     // colsum combine (4 KB)
    __shared__ float  sX[FEAT_];     // summed S row (1 KB)
    __shared__ float  sO[MEM_];      // out0 row (512 B)
    __shared__ float  sH[2][MEM_];   // half-dot partials (1 KB)
    __shared__ int    sLast;

    // ---- column-sum partial of this 256-row chunk (coalesced 1KB/wave)
    {
        const float4* Xrow = (const float4*)(X + (size_t)b * N_ * FEAT_);
        const size_t base = (size_t)(chunk * ROWS + phase) * (FEAT_ / 4) + f4;
        float4 a0 = make_float4(0.f, 0.f, 0.f, 0.f);
        float4 a1 = a0, a2 = a0, a3 = a0;
        #pragma unroll
        for (int i = 0; i < ROWS / 4; i += 4) {   // 64 loads, 4 accum chains
            float4 v0 = Xrow[base + (size_t)(4 * (i + 0)) * (FEAT_ / 4)];
            float4 v1 = Xrow[base + (size_t)(4 * (i + 1)) * (FEAT_ / 4)];
            float4 v2 = Xrow[base + (size_t)(4 * (i + 2)) * (FEAT_ / 4)];
            float4 v3 = Xrow[base + (size_t)(4 * (i + 3)) * (FEAT_ / 4)];
            a0.x += v0.x; a0.y += v0.y; a0.z += v0.z; a0.w += v0.w;
            a1.x += v1.x; a1.y += v1.y; a1.z += v1.z; a1.w += v1.w;
            a2.x += v2.x; a2.y += v2.y; a2.z += v2.z; a2.w += v2.w;
            a3.x += v3.x; a3.y += v3.y; a3.z += v3.z; a3.w += v3.w;
        }
        float4 acc;
        acc.x = (a0.x + a1.x) + (a2.x + a3.x);
        acc.y = (a0.y + a1.y) + (a2.y + a3.y);
        acc.z = (a0.z + a1.z) + (a2.z + a3.z);
        acc.w = (a0.w + a1.w) + (a2.w + a3.w);
        sacc[tid] = acc;
    }
    __syncthreads();

    if (phase == 0) {   // wave 0 combines and releases
        float4 a = sacc[f4], b1 = sacc[64 + f4], c = sacc[128 + f4], d = sacc[192 + f4];
        float4 t;
        t.x = (a.x + b1.x) + (c.x + d.x);
        t.y = (a.y + b1.y) + (c.y + d.y);
        t.z = (a.z + b1.z) + (c.z + d.z);
        t.w = (a.w + b1.w) + (c.w + d.w);
        store_f128_sc(part + ((size_t)b * CHUNKS + chunk) * FEAT_ + 4 * f4, t);
        wait_vm0();   // partial at the coherent point before the atomic
    }
    __syncthreads();
    if (tid == 0) {
        unsigned old = atomicAdd(&cnt[b * CSTRIDE], 1u);
        sLast = (old == CHUNKS - 1);   // absolute election: true last arriver
    }
    __syncthreads();
    if (!sLast) return;

    // ================= finisher for batch b =================
    // S-reduce: 32 independent coalesced loads per thread (one latency
    // exposure), fixed-order pairwise tree -> deterministic.
    {
        const float* p = part + (size_t)b * CHUNKS * FEAT_ + tid;
        float v[CHUNKS];
        #pragma unroll
        for (int c = 0; c < CHUNKS; ++c)
            v[c] = p[c * FEAT_];
        #pragma unroll
        for (int st = 1; st < CHUNKS; st <<= 1)
            #pragma unroll
            for (int c = 0; c < CHUNKS; c += 2 * st)
                v[c] += v[c + st];
        sX[tid] = v[0];
    }
    __syncthreads();

    const int m = tid & 127;
    const int h = tid >> 7;   // 2-way split of the reduction axis

    // matvec1: out0[m] = (sum_f S[f]*Wv[f][m] + N*bv[m]) / U
    // Wv reads coalesced across the 128 m-threads, L3-hot, 2 FMA chains.
    {
        const float* wp = Wv + (size_t)(h * 128) * MEM_ + m;
        const float* xp = sX + h * 128;
        float a0 = 0.f, a1 = 0.f;
        #pragma unroll 8
        for (int r = 0; r < 128; r += 2) {
            a0 = fmaf(xp[r],     wp[(size_t)r * MEM_],       a0);
            a1 = fmaf(xp[r + 1], wp[(size_t)(r + 1) * MEM_], a1);
        }
        sH[h][m] = a0 + a1;
    }
    __syncthreads();
    if (tid < MEM_)
        sO[tid] = (sH[0][tid] + sH[1][tid] + (float)N_ * bv[tid]) * (1.0f / (float)U_);
    __syncthreads();

    // matvec2 + relu: out[m] = relu(sum_k out0[k]*Wo[k][m] + bo[m])
    {
        const float* op = Wo + (size_t)(h * 64) * MEM_ + m;
        const float* vp = sO + h * 64;
        float c0 = 0.f, c1 = 0.f;
        #pragma unroll 8
        for (int r = 0; r < 64; r += 2) {
            c0 = fmaf(vp[r],     op[(size_t)r * MEM_],       c0);
            c1 = fmaf(vp[r + 1], op[(size_t)(r + 1) * MEM_], c1);
        }
        sH[h][m] = c0 + c1;
    }
    __syncthreads();
    if (tid < MEM_)
        out[b * MEM_ + tid] = fmaxf(sH[0][tid] + sH[1][tid] + bo[tid], 0.f);
}

// ---------------------------------------------------------------------------
extern "C" void kernel_launch(void* const* d_in, const int* in_sizes, int n_in,
                              void* d_out, int out_size, void* d_ws, size_t ws_size,
                              hipStream_t stream) {
    const float* X  = (const float*)d_in[0];
    // d_in[1] = mem, d_in[2] = Wk, d_in[3] = bk  -- mathematically dead
    const float* Wv = (const float*)d_in[4];
    const float* bv = (const float*)d_in[5];
    const float* Wo = (const float*)d_in[6];
    const float* bo = (const float*)d_in[7];
    float* out = (float*)d_out;

    float*    part = (float*)d_ws;                                  // 512 KiB
    unsigned* cnt  = (unsigned*)((char*)d_ws + (size_t)512 * 1024); // 2 KiB

    // Deterministic counter init each call (round-8 lesson: absolute election
    // REQUIRES a known starting value; d_ws poison is 0xAA, not 0).
    hipMemsetAsync(cnt, 0, B_ * CSTRIDE * sizeof(unsigned), stream);

    fused_all<<<dim3(B_ * CHUNKS), 256, 0, stream>>>(
        X, Wv, bv, Wo, bo, part, cnt, out);
}

// Round 10
// 31.512 us; speedup vs baseline: 1.1583x; 1.1583x over previous
//
#include <hip/hip_runtime.h>

// Problem constants (from reference)
#define B_    16
#define N_    8192
#define FEAT_ 256
#define MEM_  128
#define U_    512

#define CHUNKS  32
#define ROWS    (N_ / CHUNKS)    // 256 rows per colsum block
#define CSTRIDE 32               // per-batch counter stride in uints (128 B)

// ---------------------------------------------------------------------------
// Exact algebraic reduction of the reference:
//   softmax over u then mean over the SAME u axis => attn rows sum to 1
//   out[b,:] = relu( ((S_b @ Wv + N*bv)/U) @ Wo + bo ),  S_b[f] = sum_n X[b,n,f]
// K, mem, Wk, bk, scores, softmax are all mathematically dead.
//
// SINGLE fused kernel, SINGLE graph node. Handoff history:
//   r3: per-block __threadfence -> L2 writeback storm (135us).
//   r6: sc0sc1+vmcnt+atomic protocol CORRECT but 1024 atomics on one line
//       serialized (53us).
//   r8: modular election w/o memset -> WRONG (winner too early at poison).
//   r9: spread counters fixed atomics, but memset = a 2nd graph node anyway,
//       and the finisher used dependent-chain global matvec loads (~5-10us
//       tail) -> 36.5us, still worse than two-kernel 29.0.
// This version:
//   * NO memset node: self-normalizing election. tid0: old=atomicAdd(+1);
//     spin on d=(int)(v-old): d==32 -> I was FIRST arriver and all 32 are in
//     -> finisher (then atomicSub(32) releases spinners, net drift 0/call);
//     d<=0 -> reset observed -> exit. Correct for ANY initial counter value.
//     Winner identity may vary; winner's math is fixed-order fp32 ->
//     deterministic output. All 512 blocks co-resident (launch_bounds(256,2))
//     -> spin cannot deadlock.
//   * finisher matvecs: tiles of 16 INDEPENDENT loads into registers (one
//     latency exposure per 16) instead of dependent chains.
//   * release: sc0sc1 write-through + vmcnt(0) before the arrival atomic
//     (r6-validated); counters on separate 128-B lines (r9-validated).
// ---------------------------------------------------------------------------

__device__ inline void store_f128_sc(float* p, float4 v) {
    typedef float f4v __attribute__((ext_vector_type(4)));
    f4v w; w[0] = v.x; w[1] = v.y; w[2] = v.z; w[3] = v.w;
    asm volatile("global_store_dwordx4 %0, %1, off sc0 sc1" :: "v"(p), "v"(w) : "memory");
}
__device__ inline void wait_vm0() {
    asm volatile("s_waitcnt vmcnt(0)" ::: "memory");
}

__global__ __launch_bounds__(256, 2) void fused_all(
    const float* __restrict__ X,
    const float* __restrict__ Wv, const float* __restrict__ bv,
    const float* __restrict__ Wo, const float* __restrict__ bo,
    float* __restrict__ part,     // [B][CHUNKS][FEAT]
    unsigned* __restrict__ cnt,   // [B] counters, CSTRIDE-strided lines
    float* __restrict__ out) {
    const int bid   = blockIdx.x;
    const int chunk = bid & (CHUNKS - 1);
    const int b     = bid >> 5;
    const int tid   = threadIdx.x;
    const int f4    = tid & 63;   // which float4 of the 256-feature row
    const int phase = tid >> 6;   // 0..3 row phase

    __shared__ float4 sacc[256];     // colsum combine (4 KB)
    __shared__ float  sX[FEAT_];     // summed S row (1 KB)
    __shared__ float  sO[MEM_];      // out0 row (512 B)
    __shared__ float  sH[2][MEM_];   // half-dot partials (1 KB)
    __shared__ int    sLast;

    // ---- column-sum partial of this 256-row chunk (coalesced 1KB/wave)
    {
        const float4* Xrow = (const float4*)(X + (size_t)b * N_ * FEAT_);
        const size_t base = (size_t)(chunk * ROWS + phase) * (FEAT_ / 4) + f4;
        float4 a0 = make_float4(0.f, 0.f, 0.f, 0.f);
        float4 a1 = a0, a2 = a0, a3 = a0;
        #pragma unroll
        for (int i = 0; i < ROWS / 4; i += 4) {   // 64 loads, 4 accum chains
            float4 v0 = Xrow[base + (size_t)(4 * (i + 0)) * (FEAT_ / 4)];
            float4 v1 = Xrow[base + (size_t)(4 * (i + 1)) * (FEAT_ / 4)];
            float4 v2 = Xrow[base + (size_t)(4 * (i + 2)) * (FEAT_ / 4)];
            float4 v3 = Xrow[base + (size_t)(4 * (i + 3)) * (FEAT_ / 4)];
            a0.x += v0.x; a0.y += v0.y; a0.z += v0.z; a0.w += v0.w;
            a1.x += v1.x; a1.y += v1.y; a1.z += v1.z; a1.w += v1.w;
            a2.x += v2.x; a2.y += v2.y; a2.z += v2.z; a2.w += v2.w;
            a3.x += v3.x; a3.y += v3.y; a3.z += v3.z; a3.w += v3.w;
        }
        float4 acc;
        acc.x = (a0.x + a1.x) + (a2.x + a3.x);
        acc.y = (a0.y + a1.y) + (a2.y + a3.y);
        acc.z = (a0.z + a1.z) + (a2.z + a3.z);
        acc.w = (a0.w + a1.w) + (a2.w + a3.w);
        sacc[tid] = acc;
    }
    __syncthreads();

    if (phase == 0) {   // wave 0 combines and releases
        float4 a = sacc[f4], b1 = sacc[64 + f4], c = sacc[128 + f4], d = sacc[192 + f4];
        float4 t;
        t.x = (a.x + b1.x) + (c.x + d.x);
        t.y = (a.y + b1.y) + (c.y + d.y);
        t.z = (a.z + b1.z) + (c.z + d.z);
        t.w = (a.w + b1.w) + (c.w + d.w);
        store_f128_sc(part + ((size_t)b * CHUNKS + chunk) * FEAT_ + 4 * f4, t);
        wait_vm0();   // partial at the coherent point before the atomic
    }
    __syncthreads();

    if (tid == 0) {
        unsigned* cp = &cnt[b * CSTRIDE];
        unsigned old = atomicAdd(cp, 1u);
        int last = 0;
        for (;;) {
            unsigned v = __hip_atomic_load(cp, __ATOMIC_RELAXED,
                                           __HIP_MEMORY_SCOPE_AGENT);
            int d = (int)(v - old);
            if (d == CHUNKS) { last = 1; break; }  // first arriver, all in
            if (d <= 0)      { last = 0; break; }  // reset observed -> done
            __builtin_amdgcn_s_sleep(2);
        }
        if (last) atomicSub(cp, (unsigned)CHUNKS); // release spinners now
        sLast = last;
    }
    __syncthreads();
    if (!sLast) return;

    // ================= finisher for batch b =================
    // S-reduce: 32 independent coalesced loads (one latency exposure),
    // fixed-order pairwise tree -> deterministic.
    {
        const float* p = part + (size_t)b * CHUNKS * FEAT_ + tid;
        float v[CHUNKS];
        #pragma unroll
        for (int c = 0; c < CHUNKS; ++c)
            v[c] = p[c * FEAT_];
        #pragma unroll
        for (int st = 1; st < CHUNKS; st <<= 1)
            #pragma unroll
            for (int c = 0; c < CHUNKS; c += 2 * st)
                v[c] += v[c + st];
        sX[tid] = v[0];
    }
    __syncthreads();

    const int m = tid & 127;
    const int h = tid >> 7;   // 2-way split of the reduction axis

    // matvec1: out0[m] = (sum_f S[f]*Wv[f][m] + N*bv[m]) / U
    // Tiles of 16 INDEPENDENT loads -> ~8 latency exposures total.
    {
        const float* wvc = Wv + m;    // column m
        float acc = 0.f;
        #pragma unroll
        for (int t = 0; t < 8; ++t) {
            const int f0 = h * 128 + t * 16;
            float w[16];
            #pragma unroll
            for (int j = 0; j < 16; ++j)
                w[j] = wvc[(size_t)(f0 + j) * MEM_];
            #pragma unroll
            for (int j = 0; j < 16; ++j)
                acc = fmaf(sX[f0 + j], w[j], acc);
        }
        sH[h][m] = acc;
    }
    __syncthreads();
    if (tid < MEM_)
        sO[tid] = (sH[0][tid] + sH[1][tid] + (float)N_ * bv[tid]) * (1.0f / (float)U_);
    __syncthreads();

    // matvec2 + relu: out[m] = relu(sum_k out0[k]*Wo[k][m] + bo[m])
    {
        const float* woc = Wo + m;
        float acc = 0.f;
        #pragma unroll
        for (int t = 0; t < 4; ++t) {
            const int k0 = h * 64 + t * 16;
            float w[16];
            #pragma unroll
            for (int j = 0; j < 16; ++j)
                w[j] = woc[(size_t)(k0 + j) * MEM_];
            #pragma unroll
            for (int j = 0; j < 16; ++j)
                acc = fmaf(sO[k0 + j], w[j], acc);
        }
        sH[h][m] = acc;
    }
    __syncthreads();
    if (tid < MEM_)
        out[b * MEM_ + tid] = fmaxf(sH[0][tid] + sH[1][tid] + bo[tid], 0.f);
}

// ---------------------------------------------------------------------------
extern "C" void kernel_launch(void* const* d_in, const int* in_sizes, int n_in,
                              void* d_out, int out_size, void* d_ws, size_t ws_size,
                              hipStream_t stream) {
    const float* X  = (const float*)d_in[0];
    // d_in[1] = mem, d_in[2] = Wk, d_in[3] = bk  -- mathematically dead
    const float* Wv = (const float*)d_in[4];
    const float* bv = (const float*)d_in[5];
    const float* Wo = (const float*)d_in[6];
    const float* bo = (const float*)d_in[7];
    float* out = (float*)d_out;

    float*    part = (float*)d_ws;                                  // 512 KiB
    unsigned* cnt  = (unsigned*)((char*)d_ws + (size_t)512 * 1024); // 2 KiB
    // No counter init needed: election is self-normalizing (signed-distance
    // from each block's own ticket; winner restores the counter). Single node.

    fused_all<<<dim3(B_ * CHUNKS), 256, 0, stream>>>(
        X, Wv, bv, Wo, bo, part, cnt, out);
}

// Round 11
// 28.885 us; speedup vs baseline: 1.2637x; 1.0910x over previous
//
#include <hip/hip_runtime.h>

// Problem constants (from reference)
#define B_    16
#define N_    8192
#define FEAT_ 256
#define MEM_  128
#define U_    512

#define CHUNKS 32
#define ROWS   (N_ / CHUNKS)     // 256 rows per colsum block
#define NWF    64                // Wf-stripe blocks (4 f-rows each)
#define EXTRA  (NWF + 1)         // + 1 bf block

// ---------------------------------------------------------------------------
// Exact algebraic reduction of the reference:
//   softmax over u then mean over the SAME u axis => attn rows sum to 1
//   out[b,:] = relu( S_b @ Wf + bf ),   S_b[f] = sum_n X[b,n,f]
//   Wf = (Wv@Wo)/U  [256x128],  bf = (N/U)*(bv@Wo) + bo
// K, mem, Wk, bk, scores, softmax are all mathematically dead.
//
// FINAL STRUCTURE: two kernels (round-7 version, 28.98 us — best of 10).
// Fused single-kernel handoffs were tried three ways and all lost:
//   r3  per-block __threadfence          -> L2 writeback storm, 135 us
//   r6  1024 atomics on one cache line   -> serialized RMW,      53 us
//   r10 spread-line self-norm election   -> correct but          31.5 us
// The back-to-back graph-node dispatch is cheaper than any in-kernel
// cross-block visibility protocol on gfx950.
//
// Budget at 29 us: ~21 mandatory X read (134 MB, BW-saturated; block-count
// insensitive r2/r4) + ~1.5 k2 + ~1.5 gap + ~5 fixed graph/launch overhead.
//
// k1: 65 weight blocks (WfT/bf — hidden under the X stream) + 512 colsum
//     blocks. k2: 128 small blocks, register-batched S-reduce (one latency
//     exposure) + fused matvec + relu. Fixed-order fp32 -> deterministic.
// ---------------------------------------------------------------------------

__global__ __launch_bounds__(256) void fused_k1(
    const float* __restrict__ X,
    const float* __restrict__ Wv, const float* __restrict__ bv,
    const float* __restrict__ Wo, const float* __restrict__ bo,
    float* __restrict__ part,     // [B][CHUNKS][FEAT]
    float* __restrict__ WfT,      // [MEM][FEAT] transposed fused weight
    float* __restrict__ bf) {     // [MEM]
    const int bid = blockIdx.x;
    const int tid = threadIdx.x;

    __shared__ float4 sacc[256];        // colsum combine (4 KB)
    __shared__ float  sWv[4 * MEM_];    // 4 Wv rows (2 KB)
    __shared__ float  sB[2][MEM_];      // bf combine (1 KB)

    if (bid < NWF) {
        // ---- WfT[m][4*bid + j] = (1/U) * sum_k Wv[4*bid+j][k] * Wo[k][m]
        const float* src = Wv + (size_t)(4 * bid) * MEM_;   // 512 floats
        sWv[tid]       = src[tid];
        sWv[tid + 256] = src[tid + 256];
        __syncthreads();

        const int m = tid & 127;
        const int h = tid >> 7;          // f-pair selector
        const float* wvr0 = &sWv[(2 * h) * MEM_];
        const float* wvr1 = &sWv[(2 * h + 1) * MEM_];
        float a0 = 0.f, a1 = 0.f;
        #pragma unroll 8
        for (int k = 0; k < MEM_; ++k) {
            float w = Wo[k * MEM_ + m];  // coalesced across the 128 m-threads
            a0 = fmaf(wvr0[k], w, a0);
            a1 = fmaf(wvr1[k], w, a1);
        }
        float* dst = WfT + (size_t)m * FEAT_ + 4 * bid + 2 * h;
        dst[0] = a0 * (1.0f / (float)U_);
        dst[1] = a1 * (1.0f / (float)U_);
    } else if (bid == NWF) {
        // ---- bf[m] = (N/U) * sum_k bv[k]*Wo[k][m] + bo[m]
        const int m = tid & 127;
        const int h = tid >> 7;
        float a = 0.f;
        #pragma unroll 8
        for (int k = h * 64; k < h * 64 + 64; ++k)
            a = fmaf(bv[k], Wo[k * MEM_ + m], a);
        sB[h][m] = a;
        __syncthreads();
        if (tid < MEM_)
            bf[tid] = ((float)N_ / (float)U_) * (sB[0][tid] + sB[1][tid]) + bo[tid];
    } else {
        // ---- column-sum partial of one 256-row chunk (coalesced 1KB/wave)
        const int cid   = bid - EXTRA;
        const int chunk = cid & (CHUNKS - 1);
        const int b     = cid / CHUNKS;
        const int f4    = tid & 63;   // which float4 of the 256-feature row
        const int phase = tid >> 6;   // 0..3 row phase

        const float4* Xrow = (const float4*)(X + (size_t)b * N_ * FEAT_);
        const size_t base = (size_t)(chunk * ROWS + phase) * (FEAT_ / 4) + f4;

        float4 a0 = make_float4(0.f, 0.f, 0.f, 0.f);
        float4 a1 = a0, a2 = a0, a3 = a0;
        #pragma unroll
        for (int i = 0; i < ROWS / 4; i += 4) {   // 64 loads, 4 accum chains
            float4 v0 = Xrow[base + (size_t)(4 * (i + 0)) * (FEAT_ / 4)];
            float4 v1 = Xrow[base + (size_t)(4 * (i + 1)) * (FEAT_ / 4)];
            float4 v2 = Xrow[base + (size_t)(4 * (i + 2)) * (FEAT_ / 4)];
            float4 v3 = Xrow[base + (size_t)(4 * (i + 3)) * (FEAT_ / 4)];
            a0.x += v0.x; a0.y += v0.y; a0.z += v0.z; a0.w += v0.w;
            a1.x += v1.x; a1.y += v1.y; a1.z += v1.z; a1.w += v1.w;
            a2.x += v2.x; a2.y += v2.y; a2.z += v2.z; a2.w += v2.w;
            a3.x += v3.x; a3.y += v3.y; a3.z += v3.z; a3.w += v3.w;
        }
        float4 acc;
        acc.x = (a0.x + a1.x) + (a2.x + a3.x);
        acc.y = (a0.y + a1.y) + (a2.y + a3.y);
        acc.z = (a0.z + a1.z) + (a2.z + a3.z);
        acc.w = (a0.w + a1.w) + (a2.w + a3.w);

        sacc[tid] = acc;
        __syncthreads();

        if (phase == 0) {
            float4 a = sacc[f4], b1 = sacc[64 + f4], c = sacc[128 + f4], d = sacc[192 + f4];
            float4 t;
            t.x = (a.x + b1.x) + (c.x + d.x);
            t.y = (a.y + b1.y) + (c.y + d.y);
            t.z = (a.z + b1.z) + (c.z + d.z);
            t.w = (a.w + b1.w) + (c.w + d.w);
            ((float4*)part)[((size_t)b * CHUNKS + chunk) * (FEAT_ / 4) + f4] = t;
        }
    }
}

// ---------------------------------------------------------------------------
// k2: 128 blocks = (batch b, m-group of 16). Register-batched S-reduce
// (all 32 loads independent and in flight -> latency paid once, not 16x),
// then 16-wide segment dots against WfT, LDS combine, relu, store.
// ---------------------------------------------------------------------------
__global__ __launch_bounds__(256) void finish_k2(
    const float* __restrict__ part, const float* __restrict__ WfT,
    const float* __restrict__ bf, float* __restrict__ out) {
    const int mg  = blockIdx.x & 7;
    const int b   = blockIdx.x >> 3;
    const int tid = threadIdx.x;

    __shared__ float sX[FEAT_];
    __shared__ float sRed[16][17];   // +1 pad

    // step 1: S[f] = sum_c part[b][c][f] -- all loads independent, in regs
    {
        const float* p = part + (size_t)b * CHUNKS * FEAT_ + tid;
        float v[CHUNKS];
        #pragma unroll
        for (int c = 0; c < CHUNKS; ++c)
            v[c] = p[c * FEAT_];               // 32 loads, all in flight
        // fixed-order pairwise tree
        #pragma unroll
        for (int st = 1; st < CHUNKS; st <<= 1)
            #pragma unroll
            for (int c = 0; c < CHUNKS; c += 2 * st)
                v[c] += v[c + st];
        sX[tid] = v[0];
    }
    __syncthreads();

    // step 2: 16-wide segment dots against WfT row m
    const int mi = tid & 15;
    const int ki = tid >> 4;
    const int m  = mg * 16 + mi;
    {
        const float4* wrow = (const float4*)(WfT + (size_t)m * FEAT_ + ki * 16);
        const float4* xseg = (const float4*)(&sX[ki * 16]);
        float acc = 0.f;
        #pragma unroll
        for (int j = 0; j < 4; ++j) {
            float4 w = wrow[j];
            float4 x = xseg[j];
            acc += (w.x * x.x + w.y * x.y) + (w.z * x.z + w.w * x.w);
        }
        sRed[mi][ki] = acc;
    }
    __syncthreads();

    // step 3: combine 16 segments (fixed order), bias, relu, store
    if (tid < 16) {
        float a = 0.f;
        #pragma unroll
        for (int k = 0; k < 16; ++k)
            a += sRed[tid][k];
        const int mm = mg * 16 + tid;
        out[b * MEM_ + mm] = fmaxf(a + bf[mm], 0.f);
    }
}

// ---------------------------------------------------------------------------
extern "C" void kernel_launch(void* const* d_in, const int* in_sizes, int n_in,
                              void* d_out, int out_size, void* d_ws, size_t ws_size,
                              hipStream_t stream) {
    const float* X  = (const float*)d_in[0];
    // d_in[1] = mem, d_in[2] = Wk, d_in[3] = bk  -- mathematically dead
    const float* Wv = (const float*)d_in[4];
    const float* bv = (const float*)d_in[5];
    const float* Wo = (const float*)d_in[6];
    const float* bo = (const float*)d_in[7];
    float* out  = (float*)d_out;

    float* part = (float*)d_ws;                       // 512 KiB
    float* WfT  = part + (size_t)B_ * CHUNKS * FEAT_; // 128 KiB
    float* bf   = WfT + (size_t)MEM_ * FEAT_;         // 512 B

    fused_k1<<<dim3(EXTRA + CHUNKS * B_), 256, 0, stream>>>(
        X, Wv, bv, Wo, bo, part, WfT, bf);
    finish_k2<<<dim3(B_ * 8), 256, 0, stream>>>(part, WfT, bf, out);
}